// Round 9
// baseline (242.162 us; speedup 1.0000x reference)
//
#include <hip/hip_runtime.h>
#include <math.h>

#define DIM 64
#define SCAN_BLOCK 1024
#define NB1 1024          // coarse bins (dst>>7 <= 781 for n=100000)
#define NBLK2 256         // blocks in coarse count/scatter phases
#define TPB2 1024         // threads per block in coarse phases
#define LEN2 (NB1 * NBLK2)
#define BUCKET_BITS 7
#define BUCKET_SZ 128     // nodes per coarse bucket
#define SRC_SHIFT 20      // src fits in 17 bits; dst low-7 packed above
#define SRC_MASK ((1 << SRC_SHIFT) - 1)
#define CHUNK 4096        // edges per LDS chunk in fine_aggregate
#define FTPB 512          // fine_aggregate threads

// ---------------------------------------------------------------------------
// Kernel A: per-node scores + bf16 feature copy (single read of features).
// ---------------------------------------------------------------------------
__global__ void prep_scores_bf16(const float* __restrict__ feat,
                                 const float* __restrict__ attn_w,
                                 float* __restrict__ s_src,
                                 float* __restrict__ s_dst,
                                 unsigned short* __restrict__ fbf,
                                 int n_nodes) {
    int gid  = blockIdx.x * blockDim.x + threadIdx.x;
    int node = gid >> 4;
    int lane = gid & 15;
    if (node >= n_nodes) return;
    const float4 f  = *reinterpret_cast<const float4*>(feat + (size_t)node * DIM + lane * 4);
    const float4 as = *reinterpret_cast<const float4*>(attn_w + lane * 4);
    const float4 ad = *reinterpret_cast<const float4*>(attn_w + DIM + lane * 4);
    float ps = f.x * as.x + f.y * as.y + f.z * as.z + f.w * as.w;
    float pd = f.x * ad.x + f.y * ad.y + f.z * ad.z + f.w * ad.w;
    uint b0 = __float_as_uint(f.x), b1 = __float_as_uint(f.y);
    uint b2 = __float_as_uint(f.z), b3 = __float_as_uint(f.w);
    ushort4 h;
    h.x = (unsigned short)((b0 + 0x7FFFu + ((b0 >> 16) & 1u)) >> 16);
    h.y = (unsigned short)((b1 + 0x7FFFu + ((b1 >> 16) & 1u)) >> 16);
    h.z = (unsigned short)((b2 + 0x7FFFu + ((b2 >> 16) & 1u)) >> 16);
    h.w = (unsigned short)((b3 + 0x7FFFu + ((b3 >> 16) & 1u)) >> 16);
    *reinterpret_cast<ushort4*>(fbf + (size_t)node * DIM + lane * 4) = h;
    for (int off = 8; off >= 1; off >>= 1) {
        ps += __shfl_xor(ps, off, 16);
        pd += __shfl_xor(pd, off, 16);
    }
    if (lane == 0) {
        s_src[node] = ps;
        s_dst[node] = pd;
    }
}

// ---------------------------------------------------------------------------
// Sort phase 1: per-block LDS histogram, coalesced block-major store.
// ---------------------------------------------------------------------------
__global__ void coarse_count(const int* __restrict__ dst,
                             int* __restrict__ bcntT, int m) {
    __shared__ int lhist[NB1];
    for (int t = threadIdx.x; t < NB1; t += blockDim.x) lhist[t] = 0;
    __syncthreads();
    int chunk = (m + NBLK2 - 1) / NBLK2;
    int lo = blockIdx.x * chunk;
    int hi = min(m, lo + chunk);
    for (int i = lo + threadIdx.x; i < hi; i += blockDim.x)
        atomicAdd(&lhist[dst[i] >> BUCKET_BITS], 1);         // LDS atomic
    __syncthreads();
    for (int t = threadIdx.x; t < NB1; t += blockDim.x)
        bcntT[(size_t)blockIdx.x * NB1 + t] = lhist[t];      // coalesced
}

// ---------------------------------------------------------------------------
// Generic RxC int transpose via 32x32 LDS tiles (256 threads/block).
// ---------------------------------------------------------------------------
__global__ void transpose_mat(const int* __restrict__ in, int* __restrict__ out,
                              int R, int C) {
    __shared__ int tile[32][33];
    int tilesPerRow = C >> 5;
    int bx = blockIdx.x % tilesPerRow;
    int by = blockIdx.x / tilesPerRow;
    int tx = threadIdx.x & 31, ty = threadIdx.x >> 5;
    int x = bx * 32 + tx;
#pragma unroll
    for (int j = 0; j < 32; j += 8)
        tile[ty + j][tx] = in[(size_t)(by * 32 + ty + j) * C + x];
    __syncthreads();
    int x2 = by * 32 + tx;
#pragma unroll
    for (int j = 0; j < 32; j += 8)
        out[(size_t)(bx * 32 + ty + j) * R + x2] = tile[tx][ty + j];
}

// ---------------------------------------------------------------------------
// Phase 2: 3-level exclusive scan over the bin-major histogram (LEN2 ints)
// ---------------------------------------------------------------------------
__global__ void scan_level1(const int* __restrict__ in, int* __restrict__ out,
                            int* __restrict__ bsum, int n) {
    __shared__ int tmp[SCAN_BLOCK];
    int t = threadIdx.x;
    int g = blockIdx.x * SCAN_BLOCK + t;
    int v = (g < n) ? in[g] : 0;
    tmp[t] = v;
    __syncthreads();
    for (int off = 1; off < SCAN_BLOCK; off <<= 1) {
        int u = (t >= off) ? tmp[t - off] : 0;
        __syncthreads();
        tmp[t] += u;
        __syncthreads();
    }
    if (g < n) out[g] = tmp[t] - v;                          // exclusive
    if (t == SCAN_BLOCK - 1) bsum[blockIdx.x] = tmp[t];
}

__global__ void scan_level2(int* __restrict__ bsum, int nb) {
    __shared__ int tmp[SCAN_BLOCK];
    int t = threadIdx.x;
    int v = (t < nb) ? bsum[t] : 0;
    tmp[t] = v;
    __syncthreads();
    for (int off = 1; off < SCAN_BLOCK; off <<= 1) {
        int u = (t >= off) ? tmp[t - off] : 0;
        __syncthreads();
        tmp[t] += u;
        __syncthreads();
    }
    if (t < nb) bsum[t] = tmp[t] - v;                        // exclusive
}

__global__ void scan_level3(int* __restrict__ out, const int* __restrict__ bsum,
                            int n) {
    int g = blockIdx.x * SCAN_BLOCK + threadIdx.x;
    if (g < n) out[g] += bsum[blockIdx.x];
}

// ---------------------------------------------------------------------------
// Phase 3: scatter edges into coarse buckets; ONE packed int per edge.
// ---------------------------------------------------------------------------
__global__ void coarse_scatter(const int* __restrict__ src,
                               const int* __restrict__ dst,
                               const int* __restrict__ bposT,
                               int* __restrict__ bpk, int m) {
    __shared__ int lbase[NB1];
    for (int t = threadIdx.x; t < NB1; t += blockDim.x)
        lbase[t] = bposT[(size_t)blockIdx.x * NB1 + t];      // coalesced
    __syncthreads();
    int chunk = (m + NBLK2 - 1) / NBLK2;
    int lo = blockIdx.x * chunk;
    int hi = min(m, lo + chunk);
    for (int i = lo + threadIdx.x; i < hi; i += blockDim.x) {
        int d = dst[i];
        int p = atomicAdd(&lbase[d >> BUCKET_BITS], 1);      // LDS atomic
        bpk[p] = src[i] | ((d & (BUCKET_SZ - 1)) << SRC_SHIFT);
    }
}

// ---------------------------------------------------------------------------
// Phase 4 (FUSED fine_sort + aggregate, register accumulation, unroll-4):
// one block per 128-node bucket. Per chunk of <=4096 edges:
//   1) stage packed edges in LDS + per-dst count (int LDS atomics)
//   2) exclusive scan (128 bins) in LDS
//   3) scatter chunk into dst-sorted LDS order
//   4) weight pass: ONE expf per edge -> LDS (reuses staging buffer)
//   5) node-parallel accumulate, UNROLL-4: 4 independent 8B row gathers in
//      flight per thread (the round-6 ILP that made the gather fast).
// Epilogue: out = elu(acc/wsum), coalesced float4 stores.
// ---------------------------------------------------------------------------
__device__ __forceinline__ float lrelu(float x) { return x > 0.f ? x : 0.01f * x; }
__device__ __forceinline__ float elu(float x)  { return x > 0.f ? x : expm1f(x); }

__global__ __launch_bounds__(FTPB)
void fine_aggregate(const int* __restrict__ bpk,
                    const int* __restrict__ bcnt,
                    const float* __restrict__ s_src,
                    const float* __restrict__ s_dst,
                    const unsigned short* __restrict__ fbf,
                    float* __restrict__ out,
                    int n) {
    __shared__ int   epk[CHUNK];      // staging; reused as float wf after scatter
    __shared__ int   esrcL[CHUNK];    // dst-sorted packed edges
    __shared__ int   cnt[BUCKET_SZ];
    __shared__ int   base[BUCKET_SZ];
    __shared__ int   cursor[BUCKET_SZ];
    __shared__ int   sA[BUCKET_SZ];
    __shared__ float sdd[BUCKET_SZ];

    int b = blockIdx.x, t = threadIdx.x;
    int start = bcnt[(size_t)b * NBLK2];
    int end   = bcnt[(size_t)(b + 1) * NBLK2];
    int nodeBase = b * BUCKET_SZ;
    if (t < BUCKET_SZ) {
        int gn = nodeBase + t;
        sdd[t] = (gn < n) ? s_dst[gn] : 0.f;
    }
    float4 acc[4];
    float  wsum[4];
#pragma unroll
    for (int k = 0; k < 4; k++) {
        acc[k] = make_float4(0.f, 0.f, 0.f, 0.f);
        wsum[k] = 0.f;
    }
    int node0 = t >> 4;       // 0..31
    int lane  = t & 15;
    const uint2* fv = reinterpret_cast<const uint2*>(fbf);

    for (int clo = start; clo < end; clo += CHUNK) {
        int clen = min(CHUNK, end - clo);
        if (t < BUCKET_SZ) cnt[t] = 0;
        __syncthreads();
        // stage + count
        for (int i = t; i < clen; i += FTPB) {
            int pk = bpk[clo + i];
            epk[i] = pk;
            atomicAdd(&cnt[(pk >> SRC_SHIFT) & (BUCKET_SZ - 1)], 1);
        }
        __syncthreads();
        // exclusive scan of cnt -> base/cursor
        if (t < BUCKET_SZ) sA[t] = cnt[t];
        __syncthreads();
        for (int off = 1; off < BUCKET_SZ; off <<= 1) {
            int u = 0;
            if (t < BUCKET_SZ && t >= off) u = sA[t - off];
            __syncthreads();
            if (t < BUCKET_SZ) sA[t] += u;
            __syncthreads();
        }
        if (t < BUCKET_SZ) {
            int e0 = sA[t] - cnt[t];
            base[t] = e0;
            cursor[t] = e0;
        }
        __syncthreads();
        // scatter into sorted LDS order (keep full pk: need dlow for weights)
        for (int i = t; i < clen; i += FTPB) {
            int pk = epk[i];
            int p = atomicAdd(&cursor[(pk >> SRC_SHIFT) & (BUCKET_SZ - 1)], 1);
            esrcL[p] = pk;
        }
        __syncthreads();
        // weight pass: one expf per EDGE (not per lane), into reused epk
        float* wf = reinterpret_cast<float*>(epk);
        for (int i = t; i < clen; i += FTPB) {
            int pk = esrcL[i];
            float e = s_src[pk & SRC_MASK] + sdd[(pk >> SRC_SHIFT) & (BUCKET_SZ - 1)];
            e = (e > 0.f) ? e : 0.01f * e;
            wf[i] = __expf(e);
        }
        __syncthreads();
        // register accumulation, unroll-4: 4 independent gathers in flight
#pragma unroll
        for (int k = 0; k < 4; k++) {
            int node = node0 + 32 * k;
            int e0 = base[node];
            int eN = e0 + cnt[node];
            int e  = e0;
            for (; e + 4 <= eN; e += 4) {
                int s0 = esrcL[e]     & SRC_MASK;
                int s1 = esrcL[e + 1] & SRC_MASK;
                int s2 = esrcL[e + 2] & SRC_MASK;
                int s3 = esrcL[e + 3] & SRC_MASK;
                float w0 = wf[e], w1 = wf[e + 1], w2 = wf[e + 2], w3 = wf[e + 3];
                uint2 q0 = fv[(size_t)s0 * 16 + lane];
                uint2 q1 = fv[(size_t)s1 * 16 + lane];
                uint2 q2 = fv[(size_t)s2 * 16 + lane];
                uint2 q3 = fv[(size_t)s3 * 16 + lane];
                wsum[k] += (w0 + w1) + (w2 + w3);
                acc[k].x += w0 * __uint_as_float(q0.x << 16)
                          + w1 * __uint_as_float(q1.x << 16)
                          + w2 * __uint_as_float(q2.x << 16)
                          + w3 * __uint_as_float(q3.x << 16);
                acc[k].y += w0 * __uint_as_float(q0.x & 0xffff0000u)
                          + w1 * __uint_as_float(q1.x & 0xffff0000u)
                          + w2 * __uint_as_float(q2.x & 0xffff0000u)
                          + w3 * __uint_as_float(q3.x & 0xffff0000u);
                acc[k].z += w0 * __uint_as_float(q0.y << 16)
                          + w1 * __uint_as_float(q1.y << 16)
                          + w2 * __uint_as_float(q2.y << 16)
                          + w3 * __uint_as_float(q3.y << 16);
                acc[k].w += w0 * __uint_as_float(q0.y & 0xffff0000u)
                          + w1 * __uint_as_float(q1.y & 0xffff0000u)
                          + w2 * __uint_as_float(q2.y & 0xffff0000u)
                          + w3 * __uint_as_float(q3.y & 0xffff0000u);
            }
            for (; e < eN; e++) {
                int s0 = esrcL[e] & SRC_MASK;
                float w0 = wf[e];
                uint2 q0 = fv[(size_t)s0 * 16 + lane];
                wsum[k] += w0;
                acc[k].x += w0 * __uint_as_float(q0.x << 16);
                acc[k].y += w0 * __uint_as_float(q0.x & 0xffff0000u);
                acc[k].z += w0 * __uint_as_float(q0.y << 16);
                acc[k].w += w0 * __uint_as_float(q0.y & 0xffff0000u);
            }
        }
        __syncthreads();   // protect LDS before next chunk overwrites
    }
    // epilogue
#pragma unroll
    for (int k = 0; k < 4; k++) {
        int node = node0 + 32 * k;
        int gn = nodeBase + node;
        if (gn < n) {
            float inv = (wsum[k] > 0.f) ? 1.f / wsum[k] : 0.f;
            float4 o;
            o.x = elu(acc[k].x * inv);
            o.y = elu(acc[k].y * inv);
            o.z = elu(acc[k].z * inv);
            o.w = elu(acc[k].w * inv);
            *reinterpret_cast<float4*>(out + (size_t)gn * DIM + lane * 4) = o;
        }
    }
}

// ---------------------------------------------------------------------------
// Fallback path (global-atomic CSR, fp32 features) if ws is too small.
// ---------------------------------------------------------------------------
__global__ void compute_scores(const float* __restrict__ feat,
                               const float* __restrict__ attn_w,
                               float* __restrict__ s_src,
                               float* __restrict__ s_dst,
                               int n_nodes) {
    int gid  = blockIdx.x * blockDim.x + threadIdx.x;
    int node = gid >> 4;
    int lane = gid & 15;
    if (node >= n_nodes) return;
    const float4 f  = *reinterpret_cast<const float4*>(feat + (size_t)node * DIM + lane * 4);
    const float4 as = *reinterpret_cast<const float4*>(attn_w + lane * 4);
    const float4 ad = *reinterpret_cast<const float4*>(attn_w + DIM + lane * 4);
    float ps = f.x * as.x + f.y * as.y + f.z * as.z + f.w * as.w;
    float pd = f.x * ad.x + f.y * ad.y + f.z * ad.z + f.w * ad.w;
    for (int off = 8; off >= 1; off >>= 1) {
        ps += __shfl_xor(ps, off, 16);
        pd += __shfl_xor(pd, off, 16);
    }
    if (lane == 0) { s_src[node] = ps; s_dst[node] = pd; }
}

__global__ void degree_rank(const int* __restrict__ dst, int* __restrict__ deg,
                            int* __restrict__ rank, int m) {
    int i = blockIdx.x * blockDim.x + threadIdx.x;
    if (i >= m) return;
    rank[i] = atomicAdd(&deg[dst[i]], 1);
}

__global__ void scatter_src(const int* __restrict__ src, const int* __restrict__ dst,
                            const int* __restrict__ rank, const int* __restrict__ offs,
                            int* __restrict__ esrc, int m) {
    int i = blockIdx.x * blockDim.x + threadIdx.x;
    if (i >= m) return;
    esrc[offs[dst[i]] + rank[i]] = src[i];
}

__global__ void aggregate_f32(const int* __restrict__ esrc,
                              const int* __restrict__ offs,
                              const int* __restrict__ deg,
                              const float* __restrict__ s_src,
                              const float* __restrict__ s_dst,
                              const float* __restrict__ feat,
                              float* __restrict__ out, int n) {
    int gid  = blockIdx.x * blockDim.x + threadIdx.x;
    int node = gid >> 4;
    int lane = gid & 15;
    if (node >= n) return;
    int start = offs[node];
    int cnt   = deg[node];
    float sdd = s_dst[node];
    const float4* fv = reinterpret_cast<const float4*>(feat);
    float4 acc = {0.f, 0.f, 0.f, 0.f};
    float wsum = 0.f;
    for (int e = 0; e < cnt; e++) {
        int s0 = esrc[start + e];
        float w0 = __expf(lrelu(s_src[s0] + sdd));
        float4 f0 = fv[s0 * 16 + lane];
        wsum += w0;
        acc.x += w0 * f0.x; acc.y += w0 * f0.y;
        acc.z += w0 * f0.z; acc.w += w0 * f0.w;
    }
    float inv = (cnt > 0) ? 1.f / wsum : 0.f;
    float4 o;
    o.x = elu(acc.x * inv); o.y = elu(acc.y * inv);
    o.z = elu(acc.z * inv); o.w = elu(acc.w * inv);
    reinterpret_cast<float4*>(out)[node * 16 + lane] = o;
}

extern "C" void kernel_launch(void* const* d_in, const int* in_sizes, int n_in,
                              void* d_out, int out_size, void* d_ws, size_t ws_size,
                              hipStream_t stream) {
    const float* feat   = (const float*)d_in[0];
    const float* attn_w = (const float*)d_in[1];
    const int*   src    = (const int*)d_in[2];
    const int*   dst    = (const int*)d_in[3];

    const int n = in_sizes[0] / DIM;   // n_nodes
    const int m = in_sizes[2];         // n_edges

    float* out = (float*)d_out;

    // ws layout (int-sized slots)
    float* s_src = (float*)d_ws;                         // n
    float* s_dst = s_src + n;                            // n
    unsigned short* fbf = (unsigned short*)(s_dst + n);  // n*DIM ushorts
    int*   bsum  = (int*)(fbf + (size_t)n * DIM);        // SCAN_BLOCK
    int*   bcntT = bsum + SCAN_BLOCK;                    // LEN2 (block-major)
    int*   bcnt  = bcntT + (size_t)LEN2;                 // LEN2 (bin-major, scanned)
    int*   bpk   = bcnt + (size_t)LEN2;                  // m
    size_t need  = ((size_t)(2 + DIM / 2) * n + SCAN_BLOCK + 2 * (size_t)LEN2
                    + (size_t)m) * sizeof(int);

    if (ws_size >= need) {
        // --- main path: coarse LDS counting sort + fused fine sort/aggregate ---
        int threads = n * 16;
        prep_scores_bf16<<<(threads + 255) / 256, 256, 0, stream>>>(
            feat, attn_w, s_src, s_dst, fbf, n);

        coarse_count<<<NBLK2, TPB2, 0, stream>>>(dst, bcntT, m);

        transpose_mat<<<(NBLK2 / 32) * (NB1 / 32), 256, 0, stream>>>(
            bcntT, bcnt, NBLK2, NB1);                        // -> bin-major

        const int nb = LEN2 / SCAN_BLOCK;                    // 256
        scan_level1<<<nb, SCAN_BLOCK, 0, stream>>>(bcnt, bcnt, bsum, LEN2);
        scan_level2<<<1, SCAN_BLOCK, 0, stream>>>(bsum, nb);
        scan_level3<<<nb, SCAN_BLOCK, 0, stream>>>(bcnt, bsum, LEN2);

        transpose_mat<<<(NB1 / 32) * (NBLK2 / 32), 256, 0, stream>>>(
            bcnt, bcntT, NB1, NBLK2);                        // -> block-major bases

        coarse_scatter<<<NBLK2, TPB2, 0, stream>>>(src, dst, bcntT, bpk, m);

        int nbd = (n + BUCKET_SZ - 1) / BUCKET_SZ;           // 782
        fine_aggregate<<<nbd, FTPB, 0, stream>>>(
            bpk, bcnt, s_src, s_dst, fbf, out, n);
    } else {
        // --- fallback: global-atomic CSR path, fp32 features ---
        int* deg2  = (int*)(s_dst + n);
        int* offs2 = deg2 + n;
        int* bsum2 = offs2 + n;
        int* rank  = bsum2 + SCAN_BLOCK;
        int* esr2  = rank + m;
        int threads = n * 16;
        compute_scores<<<(threads + 255) / 256, 256, 0, stream>>>(
            feat, attn_w, s_src, s_dst, n);
        hipMemsetAsync(deg2, 0, (size_t)n * sizeof(int), stream);
        degree_rank<<<(m + 255) / 256, 256, 0, stream>>>(dst, deg2, rank, m);
        int nb2 = (n + SCAN_BLOCK - 1) / SCAN_BLOCK;
        scan_level1<<<nb2, SCAN_BLOCK, 0, stream>>>(deg2, offs2, bsum2, n);
        scan_level2<<<1, SCAN_BLOCK, 0, stream>>>(bsum2, nb2);
        scan_level3<<<nb2, SCAN_BLOCK, 0, stream>>>(offs2, bsum2, n);
        scatter_src<<<(m + 255) / 256, 256, 0, stream>>>(src, dst, rank, offs2, esr2, m);
        aggregate_f32<<<(threads + 255) / 256, 256, 0, stream>>>(
            esr2, offs2, deg2, s_src, s_dst, feat, out, n);
    }
}

// Round 10
// 230.585 us; speedup vs baseline: 1.0502x; 1.0502x over previous
//
#include <hip/hip_runtime.h>
#include <math.h>

#define DIM 64
#define SCAN_BLOCK 1024
#define NB1 2048          // coarse bins (dst>>6 <= 1562 for n=100000)
#define NBLK2 256         // blocks in coarse count/scatter phases
#define TPB2 1024         // threads per block in coarse phases
#define LEN2 (NB1 * NBLK2)
#define BUCKET_BITS 6
#define BUCKET_SZ 64      // nodes per bucket (1563 buckets -> 6.1 blocks/CU)
#define SRC_SHIFT 20      // src fits in 17 bits; dst low-6 packed above
#define SRC_MASK ((1 << SRC_SHIFT) - 1)
#define CHUNK 2560        // >= mean(2048) + 11 sigma: buckets ~always 1 chunk
#define FTPB 512          // fine_aggregate threads

// ---------------------------------------------------------------------------
// Kernel A: per-node scores + bf16 feature copy (single read of features).
// ---------------------------------------------------------------------------
__global__ void prep_scores_bf16(const float* __restrict__ feat,
                                 const float* __restrict__ attn_w,
                                 float* __restrict__ s_src,
                                 float* __restrict__ s_dst,
                                 unsigned short* __restrict__ fbf,
                                 int n_nodes) {
    int gid  = blockIdx.x * blockDim.x + threadIdx.x;
    int node = gid >> 4;
    int lane = gid & 15;
    if (node >= n_nodes) return;
    const float4 f  = *reinterpret_cast<const float4*>(feat + (size_t)node * DIM + lane * 4);
    const float4 as = *reinterpret_cast<const float4*>(attn_w + lane * 4);
    const float4 ad = *reinterpret_cast<const float4*>(attn_w + DIM + lane * 4);
    float ps = f.x * as.x + f.y * as.y + f.z * as.z + f.w * as.w;
    float pd = f.x * ad.x + f.y * ad.y + f.z * ad.z + f.w * ad.w;
    uint b0 = __float_as_uint(f.x), b1 = __float_as_uint(f.y);
    uint b2 = __float_as_uint(f.z), b3 = __float_as_uint(f.w);
    ushort4 h;
    h.x = (unsigned short)((b0 + 0x7FFFu + ((b0 >> 16) & 1u)) >> 16);
    h.y = (unsigned short)((b1 + 0x7FFFu + ((b1 >> 16) & 1u)) >> 16);
    h.z = (unsigned short)((b2 + 0x7FFFu + ((b2 >> 16) & 1u)) >> 16);
    h.w = (unsigned short)((b3 + 0x7FFFu + ((b3 >> 16) & 1u)) >> 16);
    *reinterpret_cast<ushort4*>(fbf + (size_t)node * DIM + lane * 4) = h;
    for (int off = 8; off >= 1; off >>= 1) {
        ps += __shfl_xor(ps, off, 16);
        pd += __shfl_xor(pd, off, 16);
    }
    if (lane == 0) {
        s_src[node] = ps;
        s_dst[node] = pd;
    }
}

// ---------------------------------------------------------------------------
// Sort phase 1: per-block LDS histogram, coalesced block-major store.
// ---------------------------------------------------------------------------
__global__ void coarse_count(const int* __restrict__ dst,
                             int* __restrict__ bcntT, int m) {
    __shared__ int lhist[NB1];
    for (int t = threadIdx.x; t < NB1; t += blockDim.x) lhist[t] = 0;
    __syncthreads();
    int chunk = (m + NBLK2 - 1) / NBLK2;
    int lo = blockIdx.x * chunk;
    int hi = min(m, lo + chunk);
    for (int i = lo + threadIdx.x; i < hi; i += blockDim.x)
        atomicAdd(&lhist[dst[i] >> BUCKET_BITS], 1);         // LDS atomic
    __syncthreads();
    for (int t = threadIdx.x; t < NB1; t += blockDim.x)
        bcntT[(size_t)blockIdx.x * NB1 + t] = lhist[t];      // coalesced
}

// ---------------------------------------------------------------------------
// Generic RxC int transpose via 32x32 LDS tiles (256 threads/block).
// ---------------------------------------------------------------------------
__global__ void transpose_mat(const int* __restrict__ in, int* __restrict__ out,
                              int R, int C) {
    __shared__ int tile[32][33];
    int tilesPerRow = C >> 5;
    int bx = blockIdx.x % tilesPerRow;
    int by = blockIdx.x / tilesPerRow;
    int tx = threadIdx.x & 31, ty = threadIdx.x >> 5;
    int x = bx * 32 + tx;
#pragma unroll
    for (int j = 0; j < 32; j += 8)
        tile[ty + j][tx] = in[(size_t)(by * 32 + ty + j) * C + x];
    __syncthreads();
    int x2 = by * 32 + tx;
#pragma unroll
    for (int j = 0; j < 32; j += 8)
        out[(size_t)(bx * 32 + ty + j) * R + x2] = tile[tx][ty + j];
}

// ---------------------------------------------------------------------------
// Phase 2: 3-level exclusive scan over the bin-major histogram (LEN2 ints)
// ---------------------------------------------------------------------------
__global__ void scan_level1(const int* __restrict__ in, int* __restrict__ out,
                            int* __restrict__ bsum, int n) {
    __shared__ int tmp[SCAN_BLOCK];
    int t = threadIdx.x;
    int g = blockIdx.x * SCAN_BLOCK + t;
    int v = (g < n) ? in[g] : 0;
    tmp[t] = v;
    __syncthreads();
    for (int off = 1; off < SCAN_BLOCK; off <<= 1) {
        int u = (t >= off) ? tmp[t - off] : 0;
        __syncthreads();
        tmp[t] += u;
        __syncthreads();
    }
    if (g < n) out[g] = tmp[t] - v;                          // exclusive
    if (t == SCAN_BLOCK - 1) bsum[blockIdx.x] = tmp[t];
}

__global__ void scan_level2(int* __restrict__ bsum, int nb) {
    __shared__ int tmp[SCAN_BLOCK];
    int t = threadIdx.x;
    int v = (t < nb) ? bsum[t] : 0;
    tmp[t] = v;
    __syncthreads();
    for (int off = 1; off < SCAN_BLOCK; off <<= 1) {
        int u = (t >= off) ? tmp[t - off] : 0;
        __syncthreads();
        tmp[t] += u;
        __syncthreads();
    }
    if (t < nb) bsum[t] = tmp[t] - v;                        // exclusive
}

__global__ void scan_level3(int* __restrict__ out, const int* __restrict__ bsum,
                            int n) {
    int g = blockIdx.x * SCAN_BLOCK + threadIdx.x;
    if (g < n) out[g] += bsum[blockIdx.x];
}

// ---------------------------------------------------------------------------
// Phase 3: scatter edges into coarse buckets; ONE packed int per edge.
// ---------------------------------------------------------------------------
__global__ void coarse_scatter(const int* __restrict__ src,
                               const int* __restrict__ dst,
                               const int* __restrict__ bposT,
                               int* __restrict__ bpk, int m) {
    __shared__ int lbase[NB1];
    for (int t = threadIdx.x; t < NB1; t += blockDim.x)
        lbase[t] = bposT[(size_t)blockIdx.x * NB1 + t];      // coalesced
    __syncthreads();
    int chunk = (m + NBLK2 - 1) / NBLK2;
    int lo = blockIdx.x * chunk;
    int hi = min(m, lo + chunk);
    for (int i = lo + threadIdx.x; i < hi; i += blockDim.x) {
        int d = dst[i];
        int p = atomicAdd(&lbase[d >> BUCKET_BITS], 1);      // LDS atomic
        bpk[p] = src[i] | ((d & (BUCKET_SZ - 1)) << SRC_SHIFT);
    }
}

// ---------------------------------------------------------------------------
// Phase 4 (FUSED fine_sort + aggregate, register accumulation, unroll-4):
// one block per 64-node bucket (~2048 edges). Per chunk of <=2560 edges:
//   1) stage packed edges in LDS + per-dst count (int LDS atomics)
//   2) exclusive scan (64 bins) in LDS
//   3) scatter chunk into dst-sorted LDS order
//   4) weight pass: ONE expf per edge -> LDS (reuses staging buffer)
//   5) node-parallel accumulate, unroll-4: 4 independent 8B row gathers.
// Epilogue: out = elu(acc/wsum), coalesced float4 stores.
// ---------------------------------------------------------------------------
__device__ __forceinline__ float lrelu(float x) { return x > 0.f ? x : 0.01f * x; }
__device__ __forceinline__ float elu(float x)  { return x > 0.f ? x : expm1f(x); }

__global__ __launch_bounds__(FTPB)
void fine_aggregate(const int* __restrict__ bpk,
                    const int* __restrict__ bcnt,
                    const float* __restrict__ s_src,
                    const float* __restrict__ s_dst,
                    const unsigned short* __restrict__ fbf,
                    float* __restrict__ out,
                    int n) {
    __shared__ int   epk[CHUNK];      // staging; reused as float wf after scatter
    __shared__ int   esrcL[CHUNK];    // dst-sorted packed edges
    __shared__ int   cnt[BUCKET_SZ];
    __shared__ int   base[BUCKET_SZ];
    __shared__ int   cursor[BUCKET_SZ];
    __shared__ int   sA[BUCKET_SZ];
    __shared__ float sdd[BUCKET_SZ];

    int b = blockIdx.x, t = threadIdx.x;
    int start = bcnt[(size_t)b * NBLK2];
    int end   = bcnt[(size_t)(b + 1) * NBLK2];
    int nodeBase = b * BUCKET_SZ;
    if (t < BUCKET_SZ) {
        int gn = nodeBase + t;
        sdd[t] = (gn < n) ? s_dst[gn] : 0.f;
    }
    float4 acc[2];
    float  wsum[2];
#pragma unroll
    for (int k = 0; k < 2; k++) {
        acc[k] = make_float4(0.f, 0.f, 0.f, 0.f);
        wsum[k] = 0.f;
    }
    int node0 = t >> 4;       // 0..31
    int lane  = t & 15;
    const uint2* fv = reinterpret_cast<const uint2*>(fbf);

    for (int clo = start; clo < end; clo += CHUNK) {
        int clen = min(CHUNK, end - clo);
        if (t < BUCKET_SZ) cnt[t] = 0;
        __syncthreads();
        // stage + count
        for (int i = t; i < clen; i += FTPB) {
            int pk = bpk[clo + i];
            epk[i] = pk;
            atomicAdd(&cnt[(pk >> SRC_SHIFT) & (BUCKET_SZ - 1)], 1);
        }
        __syncthreads();
        // exclusive scan of cnt -> base/cursor
        if (t < BUCKET_SZ) sA[t] = cnt[t];
        __syncthreads();
        for (int off = 1; off < BUCKET_SZ; off <<= 1) {
            int u = 0;
            if (t < BUCKET_SZ && t >= off) u = sA[t - off];
            __syncthreads();
            if (t < BUCKET_SZ) sA[t] += u;
            __syncthreads();
        }
        if (t < BUCKET_SZ) {
            int e0 = sA[t] - cnt[t];
            base[t] = e0;
            cursor[t] = e0;
        }
        __syncthreads();
        // scatter into sorted LDS order (keep full pk: need dlow for weights)
        for (int i = t; i < clen; i += FTPB) {
            int pk = epk[i];
            int p = atomicAdd(&cursor[(pk >> SRC_SHIFT) & (BUCKET_SZ - 1)], 1);
            esrcL[p] = pk;
        }
        __syncthreads();
        // weight pass: one expf per EDGE, into reused epk
        float* wf = reinterpret_cast<float*>(epk);
        for (int i = t; i < clen; i += FTPB) {
            int pk = esrcL[i];
            float e = s_src[pk & SRC_MASK] + sdd[(pk >> SRC_SHIFT) & (BUCKET_SZ - 1)];
            e = (e > 0.f) ? e : 0.01f * e;
            wf[i] = __expf(e);
        }
        __syncthreads();
        // register accumulation, unroll-4: 4 independent gathers in flight
#pragma unroll
        for (int k = 0; k < 2; k++) {
            int node = node0 + 32 * k;
            int e0 = base[node];
            int eN = e0 + cnt[node];
            int e  = e0;
            for (; e + 4 <= eN; e += 4) {
                int s0 = esrcL[e]     & SRC_MASK;
                int s1 = esrcL[e + 1] & SRC_MASK;
                int s2 = esrcL[e + 2] & SRC_MASK;
                int s3 = esrcL[e + 3] & SRC_MASK;
                float w0 = wf[e], w1 = wf[e + 1], w2 = wf[e + 2], w3 = wf[e + 3];
                uint2 q0 = fv[(size_t)s0 * 16 + lane];
                uint2 q1 = fv[(size_t)s1 * 16 + lane];
                uint2 q2 = fv[(size_t)s2 * 16 + lane];
                uint2 q3 = fv[(size_t)s3 * 16 + lane];
                wsum[k] += (w0 + w1) + (w2 + w3);
                acc[k].x += w0 * __uint_as_float(q0.x << 16)
                          + w1 * __uint_as_float(q1.x << 16)
                          + w2 * __uint_as_float(q2.x << 16)
                          + w3 * __uint_as_float(q3.x << 16);
                acc[k].y += w0 * __uint_as_float(q0.x & 0xffff0000u)
                          + w1 * __uint_as_float(q1.x & 0xffff0000u)
                          + w2 * __uint_as_float(q2.x & 0xffff0000u)
                          + w3 * __uint_as_float(q3.x & 0xffff0000u);
                acc[k].z += w0 * __uint_as_float(q0.y << 16)
                          + w1 * __uint_as_float(q1.y << 16)
                          + w2 * __uint_as_float(q2.y << 16)
                          + w3 * __uint_as_float(q3.y << 16);
                acc[k].w += w0 * __uint_as_float(q0.y & 0xffff0000u)
                          + w1 * __uint_as_float(q1.y & 0xffff0000u)
                          + w2 * __uint_as_float(q2.y & 0xffff0000u)
                          + w3 * __uint_as_float(q3.y & 0xffff0000u);
            }
            for (; e < eN; e++) {
                int s0 = esrcL[e] & SRC_MASK;
                float w0 = wf[e];
                uint2 q0 = fv[(size_t)s0 * 16 + lane];
                wsum[k] += w0;
                acc[k].x += w0 * __uint_as_float(q0.x << 16);
                acc[k].y += w0 * __uint_as_float(q0.x & 0xffff0000u);
                acc[k].z += w0 * __uint_as_float(q0.y << 16);
                acc[k].w += w0 * __uint_as_float(q0.y & 0xffff0000u);
            }
        }
        __syncthreads();   // protect LDS before next chunk overwrites
    }
    // epilogue
#pragma unroll
    for (int k = 0; k < 2; k++) {
        int node = node0 + 32 * k;
        int gn = nodeBase + node;
        if (gn < n) {
            float inv = (wsum[k] > 0.f) ? 1.f / wsum[k] : 0.f;
            float4 o;
            o.x = elu(acc[k].x * inv);
            o.y = elu(acc[k].y * inv);
            o.z = elu(acc[k].z * inv);
            o.w = elu(acc[k].w * inv);
            *reinterpret_cast<float4*>(out + (size_t)gn * DIM + lane * 4) = o;
        }
    }
}

// ---------------------------------------------------------------------------
// Fallback path (global-atomic CSR, fp32 features) if ws is too small.
// ---------------------------------------------------------------------------
__global__ void compute_scores(const float* __restrict__ feat,
                               const float* __restrict__ attn_w,
                               float* __restrict__ s_src,
                               float* __restrict__ s_dst,
                               int n_nodes) {
    int gid  = blockIdx.x * blockDim.x + threadIdx.x;
    int node = gid >> 4;
    int lane = gid & 15;
    if (node >= n_nodes) return;
    const float4 f  = *reinterpret_cast<const float4*>(feat + (size_t)node * DIM + lane * 4);
    const float4 as = *reinterpret_cast<const float4*>(attn_w + lane * 4);
    const float4 ad = *reinterpret_cast<const float4*>(attn_w + DIM + lane * 4);
    float ps = f.x * as.x + f.y * as.y + f.z * as.z + f.w * as.w;
    float pd = f.x * ad.x + f.y * ad.y + f.z * ad.z + f.w * ad.w;
    for (int off = 8; off >= 1; off >>= 1) {
        ps += __shfl_xor(ps, off, 16);
        pd += __shfl_xor(pd, off, 16);
    }
    if (lane == 0) { s_src[node] = ps; s_dst[node] = pd; }
}

__global__ void degree_rank(const int* __restrict__ dst, int* __restrict__ deg,
                            int* __restrict__ rank, int m) {
    int i = blockIdx.x * blockDim.x + threadIdx.x;
    if (i >= m) return;
    rank[i] = atomicAdd(&deg[dst[i]], 1);
}

__global__ void scatter_src(const int* __restrict__ src, const int* __restrict__ dst,
                            const int* __restrict__ rank, const int* __restrict__ offs,
                            int* __restrict__ esrc, int m) {
    int i = blockIdx.x * blockDim.x + threadIdx.x;
    if (i >= m) return;
    esrc[offs[dst[i]] + rank[i]] = src[i];
}

__global__ void aggregate_f32(const int* __restrict__ esrc,
                              const int* __restrict__ offs,
                              const int* __restrict__ deg,
                              const float* __restrict__ s_src,
                              const float* __restrict__ s_dst,
                              const float* __restrict__ feat,
                              float* __restrict__ out, int n) {
    int gid  = blockIdx.x * blockDim.x + threadIdx.x;
    int node = gid >> 4;
    int lane = gid & 15;
    if (node >= n) return;
    int start = offs[node];
    int cnt   = deg[node];
    float sdd = s_dst[node];
    const float4* fv = reinterpret_cast<const float4*>(feat);
    float4 acc = {0.f, 0.f, 0.f, 0.f};
    float wsum = 0.f;
    for (int e = 0; e < cnt; e++) {
        int s0 = esrc[start + e];
        float w0 = __expf(lrelu(s_src[s0] + sdd));
        float4 f0 = fv[s0 * 16 + lane];
        wsum += w0;
        acc.x += w0 * f0.x; acc.y += w0 * f0.y;
        acc.z += w0 * f0.z; acc.w += w0 * f0.w;
    }
    float inv = (cnt > 0) ? 1.f / wsum : 0.f;
    float4 o;
    o.x = elu(acc.x * inv); o.y = elu(acc.y * inv);
    o.z = elu(acc.z * inv); o.w = elu(acc.w * inv);
    reinterpret_cast<float4*>(out)[node * 16 + lane] = o;
}

extern "C" void kernel_launch(void* const* d_in, const int* in_sizes, int n_in,
                              void* d_out, int out_size, void* d_ws, size_t ws_size,
                              hipStream_t stream) {
    const float* feat   = (const float*)d_in[0];
    const float* attn_w = (const float*)d_in[1];
    const int*   src    = (const int*)d_in[2];
    const int*   dst    = (const int*)d_in[3];

    const int n = in_sizes[0] / DIM;   // n_nodes
    const int m = in_sizes[2];         // n_edges

    float* out = (float*)d_out;

    // ws layout (int-sized slots)
    float* s_src = (float*)d_ws;                         // n
    float* s_dst = s_src + n;                            // n
    unsigned short* fbf = (unsigned short*)(s_dst + n);  // n*DIM ushorts
    int*   bsum  = (int*)(fbf + (size_t)n * DIM);        // SCAN_BLOCK
    int*   bcntT = bsum + SCAN_BLOCK;                    // LEN2 (block-major)
    int*   bcnt  = bcntT + (size_t)LEN2;                 // LEN2 (bin-major, scanned)
    int*   bpk   = bcnt + (size_t)LEN2;                  // m
    size_t need  = ((size_t)(2 + DIM / 2) * n + SCAN_BLOCK + 2 * (size_t)LEN2
                    + (size_t)m) * sizeof(int);

    if (ws_size >= need) {
        // --- main path: coarse LDS counting sort + fused fine sort/aggregate ---
        int threads = n * 16;
        prep_scores_bf16<<<(threads + 255) / 256, 256, 0, stream>>>(
            feat, attn_w, s_src, s_dst, fbf, n);

        coarse_count<<<NBLK2, TPB2, 0, stream>>>(dst, bcntT, m);

        transpose_mat<<<(NBLK2 / 32) * (NB1 / 32), 256, 0, stream>>>(
            bcntT, bcnt, NBLK2, NB1);                        // -> bin-major

        const int nb = LEN2 / SCAN_BLOCK;                    // 512
        scan_level1<<<nb, SCAN_BLOCK, 0, stream>>>(bcnt, bcnt, bsum, LEN2);
        scan_level2<<<1, SCAN_BLOCK, 0, stream>>>(bsum, nb);
        scan_level3<<<nb, SCAN_BLOCK, 0, stream>>>(bcnt, bsum, LEN2);

        transpose_mat<<<(NB1 / 32) * (NBLK2 / 32), 256, 0, stream>>>(
            bcnt, bcntT, NB1, NBLK2);                        // -> block-major bases

        coarse_scatter<<<NBLK2, TPB2, 0, stream>>>(src, dst, bcntT, bpk, m);

        int nbd = (n + BUCKET_SZ - 1) / BUCKET_SZ;           // 1563
        fine_aggregate<<<nbd, FTPB, 0, stream>>>(
            bpk, bcnt, s_src, s_dst, fbf, out, n);
    } else {
        // --- fallback: global-atomic CSR path, fp32 features ---
        int* deg2  = (int*)(s_dst + n);
        int* offs2 = deg2 + n;
        int* bsum2 = offs2 + n;
        int* rank  = bsum2 + SCAN_BLOCK;
        int* esr2  = rank + m;
        int threads = n * 16;
        compute_scores<<<(threads + 255) / 256, 256, 0, stream>>>(
            feat, attn_w, s_src, s_dst, n);
        hipMemsetAsync(deg2, 0, (size_t)n * sizeof(int), stream);
        degree_rank<<<(m + 255) / 256, 256, 0, stream>>>(dst, deg2, rank, m);
        int nb2 = (n + SCAN_BLOCK - 1) / SCAN_BLOCK;
        scan_level1<<<nb2, SCAN_BLOCK, 0, stream>>>(deg2, offs2, bsum2, n);
        scan_level2<<<1, SCAN_BLOCK, 0, stream>>>(bsum2, nb2);
        scan_level3<<<nb2, SCAN_BLOCK, 0, stream>>>(offs2, bsum2, n);
        scatter_src<<<(m + 255) / 256, 256, 0, stream>>>(src, dst, rank, offs2, esr2, m);
        aggregate_f32<<<(threads + 255) / 256, 256, 0, stream>>>(
            esr2, offs2, deg2, s_src, s_dst, feat, out, n);
    }
}